// Round 1
// baseline (100279.132 us; speedup 1.0000x reference)
//
#include <hip/hip_runtime.h>

#define TSTEPS 4096
#define NB 6
#define FIN 128
#define HH1 512
#define HH3 128

using uint = unsigned int;

// ---------------- cross-WG communication helpers (agent scope = sc1, bypasses
// non-coherent per-XCD L2s; see guide §6 G16) ----------------

__device__ __forceinline__ float ld_agent(const float* p) {
  return __hip_atomic_load(p, __ATOMIC_RELAXED, __HIP_MEMORY_SCOPE_AGENT);
}
__device__ __forceinline__ void st_agent(float* p, float v) {
  __hip_atomic_store(p, v, __ATOMIC_RELAXED, __HIP_MEMORY_SCOPE_AGENT);
}

// Wait until all n flags >= v. Relaxed poll + one acquire fence (formally the
// C++ "fence synchronizes via atomic read" pattern).
__device__ __forceinline__ void wait_all(const uint* flags, int n, uint v, int tid) {
  if (tid < 64) {
    for (int i = tid; i < n; i += 64) {
      while (__hip_atomic_load(flags + i, __ATOMIC_RELAXED, __HIP_MEMORY_SCOPE_AGENT) < v) { }
    }
  }
  __syncthreads();
  __builtin_amdgcn_fence(__ATOMIC_ACQUIRE, "agent");
}

// Release-post this WG's flag (tid 0..47 data stores are wave 0 => the release
// store's waitcnt covers them).
__device__ __forceinline__ void post_flag(uint* flag, uint v, int tid) {
  if (tid == 0) {
    __hip_atomic_store(flag, v, __ATOMIC_RELEASE, __HIP_MEMORY_SCOPE_AGENT);
  }
}

// ---------------- matvec partial: W is [K][LC] in LDS, v is [K][NB] in LDS.
// Thread handles one column, a K-slice, all 6 batches (v reads are wave
// broadcasts; W reads are conflict-free: bank == col). ----------------
template<int LC, int KPT>
__device__ __forceinline__ void mv_part(const float* __restrict__ W, const float* __restrict__ v,
                                        int k0, int col, float acc[NB]) {
#pragma unroll
  for (int kk = 0; kk < KPT; ++kk) {
    const int k = k0 + kk;
    const float w = W[k * LC + col];
#pragma unroll
    for (int b = 0; b < NB; ++b) acc[b] += v[k * NB + b] * w;
  }
}

// ---------------- K-slice reduction + LSTM gates. NU = hidden units owned by
// this WG; local col layout = gate*NU + j. Returns h for tid < NU*6. ----------
template<int NU>
__device__ __forceinline__ float reduce_gates(const float acc[NB], float* zred, float* zfin,
                                              const float* bs, int tid, float& creg) {
  constexpr int LC = 4 * NU;
  constexpr int KS = 512 / LC;
  const int col = tid % LC;
  const int ks = tid / LC;
#pragma unroll
  for (int b = 0; b < NB; ++b) zred[(ks * LC + col) * NB + b] = acc[b];
  __syncthreads();
  if (tid < LC * NB) {
    const int c2 = tid / NB, b = tid % NB;
    float s = 0.f;
#pragma unroll
    for (int k2 = 0; k2 < KS; ++k2) s += zred[(k2 * LC + c2) * NB + b];
    zfin[c2 * NB + b] = s;
  }
  __syncthreads();
  float h = 0.f;
  if (tid < NU * NB) {
    const int j = tid / NB, b = tid % NB;
    const float zi = zfin[(0 * NU + j) * NB + b] + bs[0 * NU + j];
    const float zf = zfin[(1 * NU + j) * NB + b] + bs[1 * NU + j];
    const float zg = zfin[(2 * NU + j) * NB + b] + bs[2 * NU + j];
    const float zo = zfin[(3 * NU + j) * NB + b] + bs[3 * NU + j];
    const float ig = 1.f / (1.f + __expf(-zi));
    const float fg = 1.f / (1.f + __expf(-zf));
    const float gg = tanhf(zg);
    const float og = 1.f / (1.f + __expf(-zo));
    const float c = fg * creg + ig * gg;
    creg = c;
    h = og * tanhf(c);
  }
  return h;
}

// ================= K1: LSTM layer 1. 64 WGs x 512 thr, 8 units/WG. =========
__global__ __launch_bounds__(512) void k_l1(
    const float* __restrict__ x, const float* __restrict__ Wi, const float* __restrict__ Wh,
    const float* __restrict__ bias, float* h1buf, float* h2buf, float* c1fin, float* seq1,
    uint* flags) {
  extern __shared__ float lds[];
  float* WiS = lds;          // 128*32
  float* WhS = lds + 4096;   // 512*32
  float* xl = lds + 20480;   // 128*6
  float* hl = lds + 21248;   // 512*6
  float* zred = lds + 24320; // 3072
  float* zfin = lds + 27392; // 192
  float* bs = lds + 27584;   // 32
  const int tid = threadIdx.x;
  const int wg = blockIdx.x;
  const int u0 = wg * 8;
  // stage weight slices (cols: gate g block at local c = g*8 + j)
  for (int i = tid; i < 128 * 32; i += 512) {
    const int k = i >> 5, c = i & 31;
    WiS[i] = Wi[k * 2048 + (c >> 3) * HH1 + u0 + (c & 7)];
  }
  for (int i = tid; i < 512 * 32; i += 512) {
    const int k = i >> 5, c = i & 31;
    WhS[i] = Wh[k * 2048 + (c >> 3) * HH1 + u0 + (c & 7)];
  }
  if (tid < 32) bs[tid] = bias[(tid >> 3) * HH1 + u0 + (tid & 7)];
  __syncthreads();
  const int col = tid & 31, ks = tid >> 5;
  float creg = 0.f;
  for (int t = 0; t < TSTEPS; ++t) {
    // x[t] is [6][128]; transpose into xl[k][b]. Loads issued before the sync.
    const float* xt = x + (size_t)t * (NB * FIN);
    const float v0 = xt[tid];
    float v1 = 0.f;
    if (tid < 256) v1 = xt[512 + tid];
    __syncthreads();
    xl[(tid & 127) * NB + (tid >> 7)] = v0;
    if (tid < 256) { const int i2 = 512 + tid; xl[(i2 & 127) * NB + (i2 >> 7)] = v1; }
    __syncthreads();
    float acc[NB] = {0, 0, 0, 0, 0, 0};
    mv_part<32, 8>(WiS, xl, ks * 8, col, acc);    // x-part overlaps the wait below
    wait_all(flags, 64, (uint)t, tid);
    const float* hprev = h1buf + ((t + 1) & 1) * (HH1 * NB);
#pragma unroll
    for (int i = 0; i < 6; ++i) hl[tid + i * 512] = ld_agent(hprev + tid + i * 512);
    __syncthreads();
    mv_part<32, 32>(WhS, hl, ks * 32, col, acc);
    const float h = reduce_gates<8>(acc, zred, zfin, bs, tid, creg);
    if (tid < 48) {
      const int j = tid / 6, b = tid % 6;
      const int krow = u0 + j;
      st_agent(h1buf + (t & 1) * (HH1 * NB) + krow * NB + b, h);
      __builtin_nontemporal_store(h, seq1 + (size_t)t * (HH1 * NB) + krow * NB + b);
      if (t == TSTEPS - 1) {
        st_agent(h2buf + (HH1 * NB) + krow * NB + b, h);        // L2 initial h (parity 1)
        __builtin_nontemporal_store(creg, c1fin + krow * NB + b); // L2 initial c
      }
    }
    post_flag(flags + wg, (uint)(t + 1), tid);
  }
}

// ===== K2: LSTM layers 2+3, 1-step skew, one shared flag barrier. ===========
// WGs 0..127: L2 (4 units each). WGs 128..143: L3 (8 units each).
__global__ __launch_bounds__(512) void k_l23(
    const float* __restrict__ seq1, const float* __restrict__ Wi2, const float* __restrict__ Wh2,
    const float* __restrict__ b2, const float* __restrict__ Wi3, const float* __restrict__ Wh3,
    const float* __restrict__ b3, const float* __restrict__ c1fin,
    float* h2buf, float* h3buf, float* h3fin, uint* flags) {
  extern __shared__ float lds[];
  const int tid = threadIdx.x;
  const int wg = blockIdx.x;
  if (wg < 128) {
    float* WhS = lds;           // 512*16
    float* WiS = lds + 8192;    // 512*16
    float* xl = lds + 16384;    // 3072
    float* hl = lds + 19456;    // 3072
    float* zred = lds + 22528;  // 3072
    float* zfin = lds + 25600;  // 96
    float* bs = lds + 25696;    // 16
    const int u0 = wg * 4;
    for (int i = tid; i < 512 * 16; i += 512) {
      const int k = i >> 4, c = i & 15;
      const int cg = (c >> 2) * HH1 + u0 + (c & 3);
      WhS[i] = Wh2[k * 2048 + cg];
      WiS[i] = Wi2[k * 2048 + cg];
    }
    if (tid < 16) bs[tid] = b2[(tid >> 2) * HH1 + u0 + (tid & 3)];
    float creg = 0.f;
    if (tid < 24) creg = c1fin[(u0 + tid / 6) * NB + (tid % 6)];
    __syncthreads();
    const int col = tid & 15, ks = tid >> 4;
    for (int t = 0; t <= TSTEPS; ++t) {
      if (t < TSTEPS) {
        const float* xt = seq1 + (size_t)t * (HH1 * NB);
        float xr[6];
#pragma unroll
        for (int i = 0; i < 6; ++i) xr[i] = xt[tid + i * 512];
        __syncthreads();
#pragma unroll
        for (int i = 0; i < 6; ++i) xl[tid + i * 512] = xr[i];
        __syncthreads();
        float acc[NB] = {0, 0, 0, 0, 0, 0};
        mv_part<16, 16>(WiS, xl, ks * 16, col, acc);  // x-part overlaps the wait
        wait_all(flags, 144, (uint)t, tid);
        const float* hprev = h2buf + ((t + 1) & 1) * (HH1 * NB);
#pragma unroll
        for (int i = 0; i < 6; ++i) hl[tid + i * 512] = ld_agent(hprev + tid + i * 512);
        __syncthreads();
        mv_part<16, 16>(WhS, hl, ks * 16, col, acc);
        const float h = reduce_gates<4>(acc, zred, zfin, bs, tid, creg);
        if (tid < 24) st_agent(h2buf + (t & 1) * (HH1 * NB) + (u0 + tid / 6) * NB + (tid % 6), h);
      }
      post_flag(flags + wg, (uint)(t + 1), tid);
    }
  } else {
    float* WiS = lds;           // 512*32 (input = h2)
    float* WhS = lds + 16384;   // 128*32
    float* xl = lds + 20480;    // 3072
    float* hl = lds + 23552;    // 768
    float* zred = lds + 24320;  // 3072
    float* zfin = lds + 27392;  // 192
    float* bs = lds + 27584;    // 32
    const int u0 = (wg - 128) * 8;
    for (int i = tid; i < 512 * 32; i += 512) {
      const int k = i >> 5, c = i & 31;
      WiS[i] = Wi3[k * 512 + (c >> 3) * HH3 + u0 + (c & 7)];
    }
    for (int i = tid; i < 128 * 32; i += 512) {
      const int k = i >> 5, c = i & 31;
      WhS[i] = Wh3[k * 512 + (c >> 3) * HH3 + u0 + (c & 7)];
    }
    if (tid < 32) bs[tid] = b3[(tid >> 3) * HH3 + u0 + (tid & 7)];
    float creg = 0.f;
    __syncthreads();
    const int col = tid & 31, ks = tid >> 5;
    for (int t = 0; t <= TSTEPS; ++t) {
      if (t >= 1) {
        const int tt = t - 1;  // compute h3[tt] from h2[tt] and h3[tt-1]
        wait_all(flags, 144, (uint)t, tid);
        const float* h2p = h2buf + (tt & 1) * (HH1 * NB);
#pragma unroll
        for (int i = 0; i < 6; ++i) xl[tid + i * 512] = ld_agent(h2p + tid + i * 512);
        const float* h3p = h3buf + ((tt + 1) & 1) * (HH3 * NB);
        hl[tid] = ld_agent(h3p + tid);
        if (tid < 256) hl[512 + tid] = ld_agent(h3p + 512 + tid);
        __syncthreads();
        float acc[NB] = {0, 0, 0, 0, 0, 0};
        mv_part<32, 32>(WiS, xl, ks * 32, col, acc);
        mv_part<32, 8>(WhS, hl, ks * 8, col, acc);
        const float h = reduce_gates<8>(acc, zred, zfin, bs, tid, creg);
        if (tid < 48) {
          const int krow = u0 + tid / 6;
          st_agent(h3buf + (tt & 1) * (HH3 * NB) + krow * NB + (tid % 6), h);
          if (tt == TSTEPS - 1) __builtin_nontemporal_store(h, h3fin + krow * NB + (tid % 6));
        }
      }
      post_flag(flags + wg, (uint)(t + 1), tid);
    }
  }
}

// ================= K3: out[b] = h3[T-1][b,:] @ Wl + bl =====================
__global__ void k_out(const float* __restrict__ h3fin, const float* __restrict__ Wl,
                      const float* __restrict__ bl, float* __restrict__ out) {
  const int tid = threadIdx.x;  // 64
  float p[NB] = {0, 0, 0, 0, 0, 0};
  for (int k = tid; k < HH3; k += 64) {
    const float w = Wl[k];
#pragma unroll
    for (int b = 0; b < NB; ++b) p[b] += h3fin[k * NB + b] * w;
  }
#pragma unroll
  for (int off = 32; off > 0; off >>= 1) {
#pragma unroll
    for (int b = 0; b < NB; ++b) p[b] += __shfl_down(p[b], off);
  }
  if (tid == 0) {
#pragma unroll
    for (int b = 0; b < NB; ++b) out[b] = p[b] + bl[0];
  }
}

// ================= host launcher ===========================================
extern "C" void kernel_launch(void* const* d_in, const int* in_sizes, int n_in,
                              void* d_out, int out_size, void* d_ws, size_t ws_size,
                              hipStream_t stream) {
  (void)in_sizes; (void)n_in; (void)out_size;
  const float* x = (const float*)d_in[0];
  const float* Wi1 = (const float*)d_in[1];
  const float* Wh1 = (const float*)d_in[2];
  const float* b1 = (const float*)d_in[3];
  const float* Wi2 = (const float*)d_in[4];
  const float* Wh2 = (const float*)d_in[5];
  const float* b2 = (const float*)d_in[6];
  const float* Wi3 = (const float*)d_in[7];
  const float* Wh3 = (const float*)d_in[8];
  const float* b3 = (const float*)d_in[9];
  const float* Wl = (const float*)d_in[10];
  const float* bl = (const float*)d_in[11];

  // ws layout (floats):
  float* ws = (float*)d_ws;
  float* h1buf = ws;                     // 2*512*6 = 6144
  float* h2buf = ws + 6144;              // 6144
  float* h3buf = ws + 12288;             // 2*128*6 = 1536
  float* c1fin = ws + 13824;             // 3072
  float* h3fin = ws + 16896;             // 768
  uint* flags1 = (uint*)(ws + 17664);    // 64
  uint* flags2 = flags1 + 64;            // 144 (pads to 17920)
  float* seq1 = ws + 17920;              // 4096*3072 floats

  const size_t need = (size_t)(17920 + (size_t)TSTEPS * HH1 * NB) * sizeof(float);
  if (ws_size < need) {  // defensive: refuse to scribble past ws
    hipMemsetAsync(d_out, 0, 6 * sizeof(float), stream);
    return;
  }

  // Opt in to >64KB dynamic LDS (160KB/CU on gfx950). Not a stream op; safe
  // under graph capture; idempotent.
  hipFuncSetAttribute((const void*)k_l1, hipFuncAttributeMaxDynamicSharedMemorySize, 110464);
  hipFuncSetAttribute((const void*)k_l23, hipFuncAttributeMaxDynamicSharedMemorySize, 110464);

  // zero control region (h buffers, states, flags) — required every call.
  hipMemsetAsync(d_ws, 0, 17920 * sizeof(float), stream);

  k_l1<<<64, 512, 110464, stream>>>(x, Wi1, Wh1, b1, h1buf, h2buf, c1fin, seq1, flags1);
  k_l23<<<144, 512, 110464, stream>>>(seq1, Wi2, Wh2, b2, Wi3, Wh3, b3, c1fin,
                                      h2buf, h3buf, h3fin, flags2);
  k_out<<<1, 64, 0, stream>>>(h3fin, Wl, bl, (float*)d_out);
}

// Round 2
// 66993.011 us; speedup vs baseline: 1.4969x; 1.4969x over previous
//
#include <hip/hip_runtime.h>

#define TSTEPS 4096
#define NB 6

typedef unsigned int uint;
typedef unsigned long long u64;

// ---- relaxed agent-scope atoms (sc1; correct across non-coherent XCD L2s).
// Data+stamp travel in ONE 8-byte atom => no fences anywhere on the hot path.
__device__ __forceinline__ u64 ldp(const u64* p) {
  return __hip_atomic_load(p, __ATOMIC_RELAXED, __HIP_MEMORY_SCOPE_AGENT);
}
__device__ __forceinline__ void stp(u64* p, float v, uint s) {
  u64 x = ((u64)s << 32) | (u64)__float_as_uint(v);
  __hip_atomic_store(p, x, __ATOMIC_RELAXED, __HIP_MEMORY_SCOPE_AGENT);
}
__device__ __forceinline__ uint ldf(const uint* p) {
  return __hip_atomic_load(p, __ATOMIC_RELAXED, __HIP_MEMORY_SCOPE_AGENT);
}
__device__ __forceinline__ void stf(uint* p, uint v) {
  __hip_atomic_store(p, v, __ATOMIC_RELAXED, __HIP_MEMORY_SCOPE_AGENT);
}

__device__ __forceinline__ float sigm(float x) { return 1.f / (1.f + __expf(-x)); }

// ================= K1: LSTM layer 1. 64 WGs x 512 thr, 8 units/WG. ==========
// Weights in VGPRs (wh[32], wx[8] per thread). LDS only for h redistribution
// and the KS-partial reduction. Ring protocol: h1ring[t&7][u*6+b] =
// {val, stamp=t+1}; reader of h[t-1] spins for stamp==t (memset 0 => h[-1]=0).
__global__ __launch_bounds__(512) void k_l1(
    const float* __restrict__ x, const float* __restrict__ Wi,
    const float* __restrict__ Wh, const float* __restrict__ bias,
    u64* h1ring, u64* h2ring, float* c1fin, float* seq1) {
  __shared__ float hl[512 * 8];        // h[t-1] as [k][8]
  __shared__ float zred[16 * 32 * 8];  // KS=16 partials x 32 cols x [8]
  __shared__ float zfin[32 * 8];
  __shared__ float bs[32];
  const int tid = threadIdx.x, wg = blockIdx.x;
  const int col = tid & 31, ks = tid >> 5;  // col 0..31, ks 0..15
  const int u0 = wg * 8;
  const int gcol = ((col >> 3) * 512) + u0 + (col & 7);  // gate*H + unit
  float wh[32], wx[8];
#pragma unroll
  for (int kk = 0; kk < 32; ++kk) wh[kk] = Wh[(size_t)(ks * 32 + kk) * 2048 + gcol];
#pragma unroll
  for (int kk = 0; kk < 8; ++kk) wx[kk] = Wi[(size_t)(ks * 8 + kk) * 2048 + gcol];
  if (tid < 32) bs[tid] = bias[((tid >> 3) * 512) + u0 + (tid & 7)];
  const int gj = tid / 6, gb = tid % 6;  // gates lanes: tid<48
  float creg = 0.f;

  for (int t = 0; t < TSTEPS; ++t) {
    // ---- x-part: direct global reads (L2$/L3-resident), overlaps the wait.
    float acc[6] = {0, 0, 0, 0, 0, 0};
    {
      const float* xt = x + (size_t)t * 768;  // [6][128]
#pragma unroll
      for (int b = 0; b < 6; ++b) {
        const float4 a0 = *(const float4*)(xt + b * 128 + ks * 8);
        const float4 a1 = *(const float4*)(xt + b * 128 + ks * 8 + 4);
        acc[b] += a0.x * wx[0] + a0.y * wx[1] + a0.z * wx[2] + a0.w * wx[3] +
                  a1.x * wx[4] + a1.y * wx[5] + a1.z * wx[6] + a1.w * wx[7];
      }
    }
    // ---- stamp-fused wait + load h[t-1]: thread tid owns unit u=tid, b=0..5.
    {
      const u64* rs = h1ring + ((size_t)((t - 1) & 7)) * 3072 + tid * 6;
      u64 v[6];
      bool ok;
      do {
        ok = true;
#pragma unroll
        for (int j = 0; j < 6; ++j) {
          v[j] = ldp(rs + j);
          ok &= ((uint)(v[j] >> 32) == (uint)t);
        }
        if (!ok) __builtin_amdgcn_s_sleep(1);
      } while (!ok);
#pragma unroll
      for (int j = 0; j < 6; ++j) hl[tid * 8 + j] = __uint_as_float((uint)v[j]);
    }
    __syncthreads();  // A: hl ready; also guards all of step t-1's LDS reads
    // ---- h-part: per k one b128+b64 (broadcast within ks-group, 2-way free).
#pragma unroll
    for (int kk = 0; kk < 32; ++kk) {
      const float* hp = hl + (ks * 32 + kk) * 8;
      const float4 h0 = *(const float4*)hp;
      const float2 h1 = *(const float2*)(hp + 4);
      const float w = wh[kk];
      acc[0] += h0.x * w; acc[1] += h0.y * w; acc[2] += h0.z * w;
      acc[3] += h0.w * w; acc[4] += h1.x * w; acc[5] += h1.y * w;
    }
    {
      float* zr = zred + (ks * 32 + col) * 8;
      *(float4*)zr = make_float4(acc[0], acc[1], acc[2], acc[3]);
      *(float2*)(zr + 4) = make_float2(acc[4], acc[5]);
    }
    __syncthreads();  // B
    if (tid < 192) {
      const int c2 = tid / 6, b = tid % 6;
      float s = 0.f;
#pragma unroll
      for (int k2 = 0; k2 < 16; ++k2) s += zred[(k2 * 32 + c2) * 8 + b];
      zfin[c2 * 8 + b] = s;
    }
    __syncthreads();  // C
    if (tid < 48) {
      const float zi = zfin[(0 * 8 + gj) * 8 + gb] + bs[0 * 8 + gj];
      const float zf = zfin[(1 * 8 + gj) * 8 + gb] + bs[1 * 8 + gj];
      const float zg = zfin[(2 * 8 + gj) * 8 + gb] + bs[2 * 8 + gj];
      const float zo = zfin[(3 * 8 + gj) * 8 + gb] + bs[3 * 8 + gj];
      creg = sigm(zf) * creg + sigm(zi) * tanhf(zg);
      const float hval = sigm(zo) * tanhf(creg);
      const int gu = u0 + gj;
      stp(h1ring + ((size_t)(t & 7)) * 3072 + gu * 6 + gb, hval, (uint)(t + 1));
      seq1[(size_t)t * 4096 + gu * 8 + gb] = hval;  // padded [t][512][8]
      if (t == TSTEPS - 1) {
        ((float*)(h2ring + 7 * 3072 + gu * 6 + gb))[0] = hval;  // stamp stays 0
        c1fin[gu * 6 + gb] = creg;
      }
    }
  }
}

// ===== K2: layers 2 (WGs 0..63, 1024 thr, 8 units) and 3 (WGs 64..79). ======
// L3 consumes h2[t] directly from the stamp ring (one-way flow: constant lag,
// not per-step). flags3 (7-step slack) protects L2's ring-slot reuse (WAR).
__global__ __launch_bounds__(1024) void k_l23(
    const float* __restrict__ seq1, const float* __restrict__ Wi2,
    const float* __restrict__ Wh2, const float* __restrict__ b2,
    const float* __restrict__ Wi3, const float* __restrict__ Wh3,
    const float* __restrict__ b3, const float* __restrict__ c1fin,
    u64* h2ring, u64* h3ring, float* h3fin, uint* flags3) {
  __shared__ float hl[512 * 8];        // 16KB
  __shared__ float hl3[128 * 8];       // 4KB (L3)
  __shared__ float zred[32 * 32 * 8];  // 32KB
  __shared__ float zfin[32 * 8];
  __shared__ float bs[32];
  const int tid = threadIdx.x, wg = blockIdx.x;
  const int col = tid & 31, ks = tid >> 5;  // ks 0..31
  const int gj = tid / 6, gb = tid % 6;

  if (wg < 64) {
    // --------------- L2 ---------------
    const int u0 = wg * 8;
    const int gcol = ((col >> 3) * 512) + u0 + (col & 7);
    float wh[16], wx[16];
#pragma unroll
    for (int kk = 0; kk < 16; ++kk) {
      wh[kk] = Wh2[(size_t)(ks * 16 + kk) * 2048 + gcol];
      wx[kk] = Wi2[(size_t)(ks * 16 + kk) * 2048 + gcol];
    }
    if (tid < 32) bs[tid] = b2[((tid >> 3) * 512) + u0 + (tid & 7)];
    float creg = (tid < 48) ? c1fin[(u0 + gj) * 6 + gb] : 0.f;

    for (int t = 0; t < TSTEPS; ++t) {
      // WAR slack check: may overwrite h2[t-8]'s slot; L3 must have read it.
      if (t >= 8) {
        const uint need = (uint)(t - 7);
        while (ldf(flags3 + (tid & 15)) < need) __builtin_amdgcn_s_sleep(1);
      }
      // x-part from seq1 (global, padded [t][512][8]) — overlaps the wait.
      float acc[6] = {0, 0, 0, 0, 0, 0};
      {
        const float* xt = seq1 + (size_t)t * 4096;
#pragma unroll
        for (int kk = 0; kk < 16; ++kk) {
          const float* xp = xt + (ks * 16 + kk) * 8;
          const float4 x0 = *(const float4*)xp;
          const float2 x1 = *(const float2*)(xp + 4);
          const float w = wx[kk];
          acc[0] += x0.x * w; acc[1] += x0.y * w; acc[2] += x0.z * w;
          acc[3] += x0.w * w; acc[4] += x1.x * w; acc[5] += x1.y * w;
        }
      }
      // stamp wait + load h2[t-1]: 3 pairs per thread.
      {
        const u64* rs = h2ring + ((size_t)((t - 1) & 7)) * 3072 + tid * 3;
        u64 v[3];
        bool ok;
        do {
          ok = true;
#pragma unroll
          for (int j = 0; j < 3; ++j) {
            v[j] = ldp(rs + j);
            ok &= ((uint)(v[j] >> 32) == (uint)t);
          }
          if (!ok) __builtin_amdgcn_s_sleep(1);
        } while (!ok);
#pragma unroll
        for (int j = 0; j < 3; ++j) {
          const int p = tid * 3 + j;
          hl[(p / 6) * 8 + (p % 6)] = __uint_as_float((uint)v[j]);
        }
      }
      __syncthreads();  // A
#pragma unroll
      for (int kk = 0; kk < 16; ++kk) {
        const float* hp = hl + (ks * 16 + kk) * 8;
        const float4 h0 = *(const float4*)hp;
        const float2 h1 = *(const float2*)(hp + 4);
        const float w = wh[kk];
        acc[0] += h0.x * w; acc[1] += h0.y * w; acc[2] += h0.z * w;
        acc[3] += h0.w * w; acc[4] += h1.x * w; acc[5] += h1.y * w;
      }
      {
        float* zr = zred + (ks * 32 + col) * 8;
        *(float4*)zr = make_float4(acc[0], acc[1], acc[2], acc[3]);
        *(float2*)(zr + 4) = make_float2(acc[4], acc[5]);
      }
      __syncthreads();  // B
      if (tid < 192) {
        const int c2 = tid / 6, b = tid % 6;
        float s = 0.f;
#pragma unroll
        for (int k2 = 0; k2 < 32; ++k2) s += zred[(k2 * 32 + c2) * 8 + b];
        zfin[c2 * 8 + b] = s;
      }
      __syncthreads();  // C
      if (tid < 48) {
        const float zi = zfin[(0 * 8 + gj) * 8 + gb] + bs[0 * 8 + gj];
        const float zf = zfin[(1 * 8 + gj) * 8 + gb] + bs[1 * 8 + gj];
        const float zg = zfin[(2 * 8 + gj) * 8 + gb] + bs[2 * 8 + gj];
        const float zo = zfin[(3 * 8 + gj) * 8 + gb] + bs[3 * 8 + gj];
        creg = sigm(zf) * creg + sigm(zi) * tanhf(zg);
        const float hval = sigm(zo) * tanhf(creg);
        stp(h2ring + ((size_t)(t & 7)) * 3072 + (u0 + gj) * 6 + gb, hval, (uint)(t + 1));
      }
    }
  } else {
    // --------------- L3 ---------------
    const int wg3 = wg - 64, u0 = wg3 * 8;
    const int gcol = ((col >> 3) * 128) + u0 + (col & 7);
    float wx[16], wh[4];
#pragma unroll
    for (int kk = 0; kk < 16; ++kk) wx[kk] = Wi3[(size_t)(ks * 16 + kk) * 512 + gcol];
#pragma unroll
    for (int kk = 0; kk < 4; ++kk) wh[kk] = Wh3[(size_t)(ks * 4 + kk) * 512 + gcol];
    if (tid < 32) bs[tid] = b3[((tid >> 3) * 128) + u0 + (tid & 7)];
    float creg = 0.f;

    for (int t = 0; t < TSTEPS; ++t) {
      // wait h2[t] (stamp t+1): 3 pairs per thread.
      {
        const u64* rs = h2ring + ((size_t)(t & 7)) * 3072 + tid * 3;
        u64 v[3];
        bool ok;
        do {
          ok = true;
#pragma unroll
          for (int j = 0; j < 3; ++j) {
            v[j] = ldp(rs + j);
            ok &= ((uint)(v[j] >> 32) == (uint)(t + 1));
          }
          if (!ok) __builtin_amdgcn_s_sleep(1);
        } while (!ok);
#pragma unroll
        for (int j = 0; j < 3; ++j) {
          const int p = tid * 3 + j;
          hl[(p / 6) * 8 + (p % 6)] = __uint_as_float((uint)v[j]);
        }
      }
      // wait h3[t-1] (stamp t): 1 pair for tid<768.
      if (tid < 768) {
        const u64* rs = h3ring + ((size_t)((t - 1) & 7)) * 768 + tid;
        u64 v;
        for (;;) {
          v = ldp(rs);
          if ((uint)(v >> 32) == (uint)t) break;
          __builtin_amdgcn_s_sleep(1);
        }
        hl3[(tid / 6) * 8 + (tid % 6)] = __uint_as_float((uint)v);
      }
      __syncthreads();  // A: all h2[t] reads done => post progress (max slack)
      if (tid == 0) stf(flags3 + wg3, (uint)(t + 1));
      float acc[6] = {0, 0, 0, 0, 0, 0};
#pragma unroll
      for (int kk = 0; kk < 16; ++kk) {
        const float* hp = hl + (ks * 16 + kk) * 8;
        const float4 h0 = *(const float4*)hp;
        const float2 h1 = *(const float2*)(hp + 4);
        const float w = wx[kk];
        acc[0] += h0.x * w; acc[1] += h0.y * w; acc[2] += h0.z * w;
        acc[3] += h0.w * w; acc[4] += h1.x * w; acc[5] += h1.y * w;
      }
#pragma unroll
      for (int kk = 0; kk < 4; ++kk) {
        const float* hp = hl3 + (ks * 4 + kk) * 8;
        const float4 h0 = *(const float4*)hp;
        const float2 h1 = *(const float2*)(hp + 4);
        const float w = wh[kk];
        acc[0] += h0.x * w; acc[1] += h0.y * w; acc[2] += h0.z * w;
        acc[3] += h0.w * w; acc[4] += h1.x * w; acc[5] += h1.y * w;
      }
      {
        float* zr = zred + (ks * 32 + col) * 8;
        *(float4*)zr = make_float4(acc[0], acc[1], acc[2], acc[3]);
        *(float2*)(zr + 4) = make_float2(acc[4], acc[5]);
      }
      __syncthreads();  // B
      if (tid < 192) {
        const int c2 = tid / 6, b = tid % 6;
        float s = 0.f;
#pragma unroll
        for (int k2 = 0; k2 < 32; ++k2) s += zred[(k2 * 32 + c2) * 8 + b];
        zfin[c2 * 8 + b] = s;
      }
      __syncthreads();  // C
      if (tid < 48) {
        const float zi = zfin[(0 * 8 + gj) * 8 + gb] + bs[0 * 8 + gj];
        const float zf = zfin[(1 * 8 + gj) * 8 + gb] + bs[1 * 8 + gj];
        const float zg = zfin[(2 * 8 + gj) * 8 + gb] + bs[2 * 8 + gj];
        const float zo = zfin[(3 * 8 + gj) * 8 + gb] + bs[3 * 8 + gj];
        creg = sigm(zf) * creg + sigm(zi) * tanhf(zg);
        const float hval = sigm(zo) * tanhf(creg);
        stp(h3ring + ((size_t)(t & 7)) * 768 + (u0 + gj) * 6 + gb, hval, (uint)(t + 1));
        if (t == TSTEPS - 1) h3fin[(u0 + gj) * 6 + gb] = hval;
      }
    }
  }
}

// ================= K3: out[b] = h3[T-1][b,:] @ Wl + bl ======================
__global__ void k_out(const float* __restrict__ h3fin, const float* __restrict__ Wl,
                      const float* __restrict__ bl, float* __restrict__ out) {
  const int tid = threadIdx.x;  // 64
  float p[NB] = {0, 0, 0, 0, 0, 0};
  for (int k = tid; k < 128; k += 64) {
    const float w = Wl[k];
#pragma unroll
    for (int b = 0; b < NB; ++b) p[b] += h3fin[k * 6 + b] * w;
  }
#pragma unroll
  for (int off = 32; off > 0; off >>= 1) {
#pragma unroll
    for (int b = 0; b < NB; ++b) p[b] += __shfl_down(p[b], off);
  }
  if (tid == 0) {
#pragma unroll
    for (int b = 0; b < NB; ++b) out[b] = p[b] + bl[0];
  }
}

// ================= host launcher ============================================
extern "C" void kernel_launch(void* const* d_in, const int* in_sizes, int n_in,
                              void* d_out, int out_size, void* d_ws, size_t ws_size,
                              hipStream_t stream) {
  (void)in_sizes; (void)n_in; (void)out_size;
  const float* x   = (const float*)d_in[0];
  const float* Wi1 = (const float*)d_in[1];
  const float* Wh1 = (const float*)d_in[2];
  const float* b1  = (const float*)d_in[3];
  const float* Wi2 = (const float*)d_in[4];
  const float* Wh2 = (const float*)d_in[5];
  const float* b2  = (const float*)d_in[6];
  const float* Wi3 = (const float*)d_in[7];
  const float* Wh3 = (const float*)d_in[8];
  const float* b3  = (const float*)d_in[9];
  const float* Wl  = (const float*)d_in[10];
  const float* bl  = (const float*)d_in[11];

  // ws layout (bytes):
  //   [0)        h1ring: 8*3072 u64   = 196608
  //   [196608)   h2ring: 8*3072 u64   = 196608
  //   [393216)   h3ring: 8*768  u64   =  49152
  //   [442368)   c1fin : 3072 f       =  12288
  //   [454656)   h3fin : 768 f        =   3072
  //   [457728)   flags3: 16 u32       =     64
  //   [458752)   seq1  : 4096*512*8 f = 67108864   (padded [t][512][8])
  char* wsb = (char*)d_ws;
  u64*  h1ring = (u64*)(wsb + 0);
  u64*  h2ring = (u64*)(wsb + 196608);
  u64*  h3ring = (u64*)(wsb + 393216);
  float* c1fin = (float*)(wsb + 442368);
  float* h3fin = (float*)(wsb + 454656);
  uint* flags3 = (uint*)(wsb + 457728);
  float* seq1  = (float*)(wsb + 458752);

  const size_t need = 458752 + (size_t)TSTEPS * 512 * 8 * sizeof(float);
  if (ws_size < need) {
    hipMemsetAsync(d_out, 0, 6 * sizeof(float), stream);
    return;
  }

  // reset rings/stamps/flags/state every call (graph-replay safe).
  hipMemsetAsync(d_ws, 0, 458752, stream);

  k_l1<<<64, 512, 0, stream>>>(x, Wi1, Wh1, b1, h1ring, h2ring, c1fin, seq1);
  k_l23<<<80, 1024, 0, stream>>>(seq1, Wi2, Wh2, b2, Wi3, Wh3, b3, c1fin,
                                 h2ring, h3ring, h3fin, flags3);
  k_out<<<1, 64, 0, stream>>>(h3fin, Wl, bl, (float*)d_out);
}

// Round 3
// 44905.161 us; speedup vs baseline: 2.2331x; 1.4919x over previous
//
#include <hip/hip_runtime.h>

#define TT 4096
#define NB 6

typedef unsigned int uint;
typedef unsigned long long u64;

// ---- relaxed agent-scope atoms (sc1): correct across non-coherent XCD L2s.
__device__ __forceinline__ u64 ldp(const u64* p) {
  return __hip_atomic_load(p, __ATOMIC_RELAXED, __HIP_MEMORY_SCOPE_AGENT);
}
__device__ __forceinline__ void stp(u64* p, float v, uint s) {
  u64 x = ((u64)s << 32) | (u64)__float_as_uint(v);
  __hip_atomic_store(p, x, __ATOMIC_RELAXED, __HIP_MEMORY_SCOPE_AGENT);
}
__device__ __forceinline__ uint ldf(const uint* p) {
  return __hip_atomic_load(p, __ATOMIC_RELAXED, __HIP_MEMORY_SCOPE_AGENT);
}
__device__ __forceinline__ void stf(uint* p, uint v) {
  __hip_atomic_store(p, v, __ATOMIC_RELAXED, __HIP_MEMORY_SCOPE_AGENT);
}

__device__ __forceinline__ float sigm(float x) { return 1.f / (1.f + __expf(-x)); }
__device__ __forceinline__ float ftanh(float x) {
  x = fminf(fmaxf(x, -15.f), 15.f);
  const float e = __expf(-2.f * x);
  return (1.f - e) / (1.f + e);
}

// wave-local LDS fence: my wave's ds_writes complete before my ds_reads.
__device__ __forceinline__ void lds_wave_fence() {
  asm volatile("s_waitcnt lgkmcnt(0)" ::: "memory");
  __builtin_amdgcn_sched_barrier(0);
}

// poll 6 consecutive atoms (one unit, b=0..5) for stamp st; sentinel-first.
__device__ __forceinline__ void poll6(const u64* rs, uint st, float out[6]) {
  u64 a0;
  for (;;) {
    a0 = ldp(rs);
    if ((uint)(a0 >> 32) == st) break;
    __builtin_amdgcn_s_sleep(1);
  }
  u64 a1, a2, a3, a4, a5;
  for (;;) {
    a1 = ldp(rs + 1); a2 = ldp(rs + 2); a3 = ldp(rs + 3);
    a4 = ldp(rs + 4); a5 = ldp(rs + 5);
    if (((uint)(a1 >> 32) == st) & ((uint)(a2 >> 32) == st) &
        ((uint)(a3 >> 32) == st) & ((uint)(a4 >> 32) == st) &
        ((uint)(a5 >> 32) == st)) break;
    __builtin_amdgcn_s_sleep(1);
  }
  out[0] = __uint_as_float((uint)a0); out[1] = __uint_as_float((uint)a1);
  out[2] = __uint_as_float((uint)a2); out[3] = __uint_as_float((uint)a3);
  out[4] = __uint_as_float((uint)a4); out[5] = __uint_as_float((uint)a5);
}

// f2x3 dot-accumulate: acc[b] += v[k*6+b] * w over one k.
__device__ __forceinline__ void fma6(const float* vp, float w, float acc[6]) {
  const float2 v0 = *(const float2*)(vp);
  const float2 v1 = *(const float2*)(vp + 2);
  const float2 v2 = *(const float2*)(vp + 4);
  acc[0] += v0.x * w; acc[1] += v0.y * w; acc[2] += v1.x * w;
  acc[3] += v1.y * w; acc[4] += v2.x * w; acc[5] += v2.y * w;
}

// ================= K1: LSTM layer 1 — 64 WGs x 512 thr, 8 units/WG ==========
// lane=col-half split: col=lane&31 (4 gates x 8 units), half=lane>>5.
// wave w owns h-k-slice [64w,64w+64), x-k-slice [16w,16w+16); each half 1/2.
// Thread tid polls unit tid's 6 atoms (self-wave slice => no barrier to FMA).
__global__ __launch_bounds__(512, 2) void k_l1(
    const float* __restrict__ x, const float* __restrict__ Wi,
    const float* __restrict__ Wh, const float* __restrict__ bias,
    u64* h1ring, u64* h2ring, float* c1fin, float* seq1) {
  __shared__ float xl[2][128 * 6];
  __shared__ float hl[512 * 6];
  __shared__ float zred[16 * 32 * 8];
  __shared__ float zfin[32 * 6];
  __shared__ float bs[32];
  const int tid = threadIdx.x, wg = blockIdx.x;
  const int lane = tid & 63, w = tid >> 6;
  const int half = lane >> 5, c = lane & 31;
  const int u0 = wg * 8;
  const int gcol = ((c >> 3) * 512) + u0 + (c & 7);
  float wh[32], wx[8];
  {
    const int kh = w * 64 + half * 32, kx = w * 16 + half * 8;
#pragma unroll
    for (int kk = 0; kk < 32; ++kk) wh[kk] = Wh[(size_t)(kh + kk) * 2048 + gcol];
#pragma unroll
    for (int kk = 0; kk < 8; ++kk) wx[kk] = Wi[(size_t)(kx + kk) * 2048 + gcol];
  }
  if (tid < 32) bs[tid] = bias[((tid >> 3) * 512) + u0 + (tid & 7)];
  const int gj = tid / 6, gb = tid % 6;  // gate lanes: tid<48
  float creg = 0.f;
  // prologue: stage x[0] into xl[0] (transpose [b][k] -> [k][6])
  {
    const float v0 = x[tid];
    float v1 = 0.f;
    if (tid < 256) v1 = x[512 + tid];
    xl[0][(tid & 127) * 6 + (tid >> 7)] = v0;
    if (tid < 256) { const int i = 512 + tid; xl[0][(i & 127) * 6 + (i >> 7)] = v1; }
  }
  __syncthreads();

  for (int t = 0; t < TT; ++t) {
    // prefetch x[t+1] (registers; consumed at stage below => latency hidden)
    const float* xn = x + (size_t)((t + 1 < TT) ? t + 1 : TT - 1) * 768;
    const float v0p = xn[tid];
    float v1p = 0.f;
    if (tid < 256) v1p = xn[512 + tid];
    // x-part from xl[t&1] (pre-wait; overlaps the poll)
    float acc[6] = {0, 0, 0, 0, 0, 0};
    {
      const float* xb = xl[t & 1] + (size_t)(w * 16 + half * 8) * 6;
#pragma unroll
      for (int kk = 0; kk < 8; ++kk) fma6(xb + kk * 6, wx[kk], acc);
    }
    // poll h[t-1]: unit tid (producer WG tid>>3), stamp t
    {
      float hv[6];
      poll6(h1ring + (size_t)((t + 7) & 7) * 3072 + tid * 6, (uint)t, hv);
      float* hp = hl + tid * 6;
      *(float2*)(hp) = make_float2(hv[0], hv[1]);
      *(float2*)(hp + 2) = make_float2(hv[2], hv[3]);
      *(float2*)(hp + 4) = make_float2(hv[4], hv[5]);
    }
    lds_wave_fence();  // self-wave slice: writes [64w,64w+64) == reads below
    {
      const float* hb = hl + (size_t)(w * 64 + half * 32) * 6;
#pragma unroll
      for (int kk = 0; kk < 32; ++kk) fma6(hb + kk * 6, wh[kk], acc);
    }
    {
      float* zr = zred + (size_t)((w * 2 + half) * 32 + c) * 8;
      *(float4*)zr = make_float4(acc[0], acc[1], acc[2], acc[3]);
      *(float2*)(zr + 4) = make_float2(acc[4], acc[5]);
    }
    // stage xl[(t+1)&1] from prefetch regs
    {
      float* xs = xl[(t + 1) & 1];
      xs[(tid & 127) * 6 + (tid >> 7)] = v0p;
      if (tid < 256) { const int i = 512 + tid; xs[(i & 127) * 6 + (i >> 7)] = v1p; }
    }
    __syncthreads();  // B: zred + next xl ready
    if (tid < 192) {
      const int cc = tid / 6, bb = tid % 6;
      float s = 0.f;
#pragma unroll
      for (int p = 0; p < 16; ++p) s += zred[(p * 32 + cc) * 8 + bb];
      zfin[cc * 6 + bb] = s;
    }
    __syncthreads();  // C
    if (tid < 48) {
      __builtin_amdgcn_s_setprio(1);
      const float zi = zfin[(0 * 8 + gj) * 6 + gb] + bs[0 * 8 + gj];
      const float zf = zfin[(1 * 8 + gj) * 6 + gb] + bs[1 * 8 + gj];
      const float zg = zfin[(2 * 8 + gj) * 6 + gb] + bs[2 * 8 + gj];
      const float zo = zfin[(3 * 8 + gj) * 6 + gb] + bs[3 * 8 + gj];
      creg = sigm(zf) * creg + sigm(zi) * ftanh(zg);
      const float hval = sigm(zo) * ftanh(creg);
      const int gu = u0 + gj;
      stp(h1ring + (size_t)(t & 7) * 3072 + gu * 6 + gb, hval, (uint)(t + 1));
      seq1[(size_t)t * 4096 + gu * 8 + gb] = hval;  // padded [t][512][8]
      if (t == TT - 1) {
        stp(h2ring + (size_t)7 * 3072 + gu * 6 + gb, hval, 0u);  // L2 h-init
        c1fin[gu * 6 + gb] = creg;
      }
      __builtin_amdgcn_s_setprio(0);
    }
  }
}

// ===== K2: L2 (WGs 0..63, 8 units) + L3 (WGs 64..71, 16 units), skewed ======
__global__ __launch_bounds__(512, 2) void k_l23(
    const float* __restrict__ seq1, const float* __restrict__ Wi2,
    const float* __restrict__ Wh2, const float* __restrict__ b2,
    const float* __restrict__ Wi3, const float* __restrict__ Wh3,
    const float* __restrict__ b3, const float* __restrict__ c1fin,
    u64* h2ring, u64* h3ring, float* h3fin, uint* flags3) {
  __shared__ float smem[13536];
  const int tid = threadIdx.x, wg = blockIdx.x;
  const int lane = tid & 63, w = tid >> 6;
  const int gj = tid / 6, gb = tid % 6;

  if (wg < 64) {
    // ---------------- L2: 8 units/WG; x = seq1 row (K=512), h (K=512) -------
    float* xls = smem;            // 2 x 3072
    float* hl = smem + 6144;      // 3072
    float* zred = smem + 9216;    // 4096
    float* zfin = smem + 13312;   // 192
    float* bsl = smem + 13504;    // 32
    const int half = lane >> 5, c = lane & 31;
    const int u0 = wg * 8;
    const int gcol = ((c >> 3) * 512) + u0 + (c & 7);
    float wh[32], wx[32];
    {
      const int kb = w * 64 + half * 32;
#pragma unroll
      for (int kk = 0; kk < 32; ++kk) {
        wh[kk] = Wh2[(size_t)(kb + kk) * 2048 + gcol];
        wx[kk] = Wi2[(size_t)(kb + kk) * 2048 + gcol];
      }
    }
    if (tid < 32) bsl[tid] = b2[((tid >> 3) * 512) + u0 + (tid & 7)];
    float creg = (tid < 48) ? c1fin[(u0 + gj) * 6 + gb] : 0.f;
    // prologue: stage seq1[0]
    {
      const float4 s0 = *(const float4*)(seq1 + (size_t)tid * 8);
      const float4 s1 = *(const float4*)(seq1 + (size_t)tid * 8 + 4);
      float* xs = xls;
      *(float2*)(xs + tid * 6) = make_float2(s0.x, s0.y);
      *(float2*)(xs + tid * 6 + 2) = make_float2(s0.z, s0.w);
      *(float2*)(xs + tid * 6 + 4) = make_float2(s1.x, s1.y);
    }
    __syncthreads();

    for (int t = 0; t < TT; ++t) {
      // WAR vs L3 (amortized 4x): before overwriting slots t..t+3 need L3>=t-4
      if ((t & 3) == 0 && t >= 8 && tid < 48) {
        const uint need = (uint)(t - 4);
        while (ldf(flags3 + (tid & 7)) < need) __builtin_amdgcn_s_sleep(1);
      }
      // prefetch seq1[t+1]
      const float* sn = seq1 + (size_t)((t + 1 < TT) ? t + 1 : TT - 1) * 4096;
      const float4 p0 = *(const float4*)(sn + (size_t)tid * 8);
      const float4 p1 = *(const float4*)(sn + (size_t)tid * 8 + 4);
      // x-part (pre-wait)
      float acc[6] = {0, 0, 0, 0, 0, 0};
      {
        const float* xb = xls + (size_t)(t & 1) * 3072 + (size_t)(w * 64 + half * 32) * 6;
#pragma unroll
        for (int kk = 0; kk < 32; ++kk) fma6(xb + kk * 6, wx[kk], acc);
      }
      // poll h2[t-1]: unit tid (producer WG tid>>3), stamp t
      {
        float hv[6];
        poll6(h2ring + (size_t)((t + 7) & 7) * 3072 + tid * 6, (uint)t, hv);
        float* hp = hl + tid * 6;
        *(float2*)(hp) = make_float2(hv[0], hv[1]);
        *(float2*)(hp + 2) = make_float2(hv[2], hv[3]);
        *(float2*)(hp + 4) = make_float2(hv[4], hv[5]);
      }
      lds_wave_fence();
      {
        const float* hb = hl + (size_t)(w * 64 + half * 32) * 6;
#pragma unroll
        for (int kk = 0; kk < 32; ++kk) fma6(hb + kk * 6, wh[kk], acc);
      }
      {
        float* zr = zred + (size_t)((w * 2 + half) * 32 + c) * 8;
        *(float4*)zr = make_float4(acc[0], acc[1], acc[2], acc[3]);
        *(float2*)(zr + 4) = make_float2(acc[4], acc[5]);
      }
      {  // stage xls[(t+1)&1]
        float* xs = xls + (size_t)((t + 1) & 1) * 3072;
        *(float2*)(xs + tid * 6) = make_float2(p0.x, p0.y);
        *(float2*)(xs + tid * 6 + 2) = make_float2(p0.z, p0.w);
        *(float2*)(xs + tid * 6 + 4) = make_float2(p1.x, p1.y);
      }
      __syncthreads();  // B
      if (tid < 192) {
        const int cc = tid / 6, bb = tid % 6;
        float s = 0.f;
#pragma unroll
        for (int p = 0; p < 16; ++p) s += zred[(p * 32 + cc) * 8 + bb];
        zfin[cc * 6 + bb] = s;
      }
      __syncthreads();  // C
      if (tid < 48) {
        __builtin_amdgcn_s_setprio(1);
        const float zi = zfin[(0 * 8 + gj) * 6 + gb] + bsl[0 * 8 + gj];
        const float zf = zfin[(1 * 8 + gj) * 6 + gb] + bsl[1 * 8 + gj];
        const float zg = zfin[(2 * 8 + gj) * 6 + gb] + bsl[2 * 8 + gj];
        const float zo = zfin[(3 * 8 + gj) * 6 + gb] + bsl[3 * 8 + gj];
        creg = sigm(zf) * creg + sigm(zi) * ftanh(zg);
        const float hval = sigm(zo) * ftanh(creg);
        stp(h2ring + (size_t)(t & 7) * 3072 + (u0 + gj) * 6 + gb, hval, (uint)(t + 1));
        __builtin_amdgcn_s_setprio(0);
      }
    }
  } else {
    // ---------------- L3: 8 WGs x 16 units; x = h2 live (K=512), h3 (K=128) --
    float* hl2 = smem;            // 3072
    float* hl3 = smem + 3072;     // 768
    float* zred = smem + 3840;    // 4096
    float* zfin = smem + 7936;    // 384
    float* bsl = smem + 8320;     // 64
    const int wg3 = wg - 64;
    const int c = lane;  // 64 cols: 4 gates x 16 units
    const int u0 = wg3 * 16;
    const int gcol = ((c >> 4) * 128) + u0 + (c & 15);
    float wxh2[64], wh3[16];
#pragma unroll
    for (int kk = 0; kk < 64; ++kk) wxh2[kk] = Wi3[(size_t)(w * 64 + kk) * 512 + gcol];
#pragma unroll
    for (int kk = 0; kk < 16; ++kk) wh3[kk] = Wh3[(size_t)(w * 16 + kk) * 512 + gcol];
    if (tid < 64) bsl[tid] = b3[((tid >> 4) * 128) + u0 + (tid & 15)];
    float creg = 0.f;

    for (int t = 0; t < TT; ++t) {
      // poll h3[t-1]: wave w needs atoms [96w, 96w+96)
      {
        const u64* rs3 = h3ring + (size_t)((t + 7) & 7) * 768;
        const int a = 96 * w + lane;
        u64 v;
        for (;;) { v = ldp(rs3 + a); if ((uint)(v >> 32) == (uint)t) break; __builtin_amdgcn_s_sleep(1); }
        hl3[a] = __uint_as_float((uint)v);
        if (lane < 32) {
          const int a2 = a + 64;
          u64 v2;
          for (;;) { v2 = ldp(rs3 + a2); if ((uint)(v2 >> 32) == (uint)t) break; __builtin_amdgcn_s_sleep(1); }
          hl3[a2] = __uint_as_float((uint)v2);
        }
      }
      // poll h2[t]: unit tid (producer L2-WG tid>>3), stamp t+1
      {
        float hv[6];
        poll6(h2ring + (size_t)(t & 7) * 3072 + tid * 6, (uint)(t + 1), hv);
        float* hp = hl2 + tid * 6;
        *(float2*)(hp) = make_float2(hv[0], hv[1]);
        *(float2*)(hp + 2) = make_float2(hv[2], hv[3]);
        *(float2*)(hp + 4) = make_float2(hv[4], hv[5]);
      }
      lds_wave_fence();
      float acc[6] = {0, 0, 0, 0, 0, 0};
      {
        const float* hb = hl2 + (size_t)(w * 64) * 6;
#pragma unroll
        for (int kk = 0; kk < 64; ++kk) fma6(hb + kk * 6, wxh2[kk], acc);
        const float* h3b = hl3 + (size_t)(w * 16) * 6;
#pragma unroll
        for (int kk = 0; kk < 16; ++kk) fma6(h3b + kk * 6, wh3[kk], acc);
      }
      {
        float* zr = zred + (size_t)(w * 64 + c) * 8;
        *(float4*)zr = make_float4(acc[0], acc[1], acc[2], acc[3]);
        *(float2*)(zr + 4) = make_float2(acc[4], acc[5]);
      }
      __syncthreads();  // B: also means all h2[t] reads done
      if (tid == 0) stf(flags3 + wg3, (uint)(t + 1));
      if (tid < 384) {
        const int cc = tid / 6, bb = tid % 6;
        float s = 0.f;
#pragma unroll
        for (int p = 0; p < 8; ++p) s += zred[(p * 64 + cc) * 8 + bb];
        zfin[cc * 6 + bb] = s;
      }
      __syncthreads();  // C
      if (tid < 96) {
        __builtin_amdgcn_s_setprio(1);
        const float zi = zfin[(0 * 16 + gj) * 6 + gb] + bsl[0 * 16 + gj];
        const float zf = zfin[(1 * 16 + gj) * 6 + gb] + bsl[1 * 16 + gj];
        const float zg = zfin[(2 * 16 + gj) * 6 + gb] + bsl[2 * 16 + gj];
        const float zo = zfin[(3 * 16 + gj) * 6 + gb] + bsl[3 * 16 + gj];
        creg = sigm(zf) * creg + sigm(zi) * ftanh(zg);
        const float hval = sigm(zo) * ftanh(creg);
        stp(h3ring + (size_t)(t & 7) * 768 + (u0 + gj) * 6 + gb, hval, (uint)(t + 1));
        if (t == TT - 1) h3fin[(u0 + gj) * 6 + gb] = hval;
        __builtin_amdgcn_s_setprio(0);
      }
    }
  }
}

// ================= K3: out[b] = h3fin[:,b] @ Wl + bl ========================
__global__ void k_out(const float* __restrict__ h3fin, const float* __restrict__ Wl,
                      const float* __restrict__ bl, float* __restrict__ out) {
  const int tid = threadIdx.x;  // 64
  float p[NB] = {0, 0, 0, 0, 0, 0};
  for (int k = tid; k < 128; k += 64) {
    const float w = Wl[k];
#pragma unroll
    for (int b = 0; b < NB; ++b) p[b] += h3fin[k * 6 + b] * w;
  }
#pragma unroll
  for (int off = 32; off > 0; off >>= 1) {
#pragma unroll
    for (int b = 0; b < NB; ++b) p[b] += __shfl_down(p[b], off);
  }
  if (tid == 0) {
#pragma unroll
    for (int b = 0; b < NB; ++b) out[b] = p[b] + bl[0];
  }
}

// ================= host launcher ============================================
extern "C" void kernel_launch(void* const* d_in, const int* in_sizes, int n_in,
                              void* d_out, int out_size, void* d_ws, size_t ws_size,
                              hipStream_t stream) {
  (void)in_sizes; (void)n_in; (void)out_size;
  const float* x   = (const float*)d_in[0];
  const float* Wi1 = (const float*)d_in[1];
  const float* Wh1 = (const float*)d_in[2];
  const float* b1  = (const float*)d_in[3];
  const float* Wi2 = (const float*)d_in[4];
  const float* Wh2 = (const float*)d_in[5];
  const float* b2  = (const float*)d_in[6];
  const float* Wi3 = (const float*)d_in[7];
  const float* Wh3 = (const float*)d_in[8];
  const float* b3  = (const float*)d_in[9];
  const float* Wl  = (const float*)d_in[10];
  const float* bl  = (const float*)d_in[11];

  // ws layout (bytes):
  //   [0)       h1ring: 8*3072 u64 = 196608
  //   [196608)  h2ring: 8*3072 u64 = 196608
  //   [393216)  h3ring: 8*768  u64 =  49152
  //   [442368)  c1fin : 3072 f     =  12288
  //   [454656)  h3fin : 768 f      =   3072
  //   [457728)  flags3: 8 u32      (pad to 458752)
  //   [458752)  seq1  : 4096*512*8 f = 67108864  (padded [t][512][8])
  char* wsb = (char*)d_ws;
  u64*  h1ring = (u64*)(wsb + 0);
  u64*  h2ring = (u64*)(wsb + 196608);
  u64*  h3ring = (u64*)(wsb + 393216);
  float* c1fin = (float*)(wsb + 442368);
  float* h3fin = (float*)(wsb + 454656);
  uint* flags3 = (uint*)(wsb + 457728);
  float* seq1  = (float*)(wsb + 458752);

  const size_t need = 458752 + (size_t)TT * 512 * 8 * sizeof(float);
  if (ws_size < need) {
    hipMemsetAsync(d_out, 0, 6 * sizeof(float), stream);
    return;
  }

  // reset rings/stamps/flags/state every call (graph-replay safe).
  hipMemsetAsync(d_ws, 0, 458752, stream);

  k_l1<<<64, 512, 0, stream>>>(x, Wi1, Wh1, b1, h1ring, h2ring, c1fin, seq1);
  k_l23<<<72, 512, 0, stream>>>(seq1, Wi2, Wh2, b2, Wi3, Wh3, b3, c1fin,
                                h2ring, h3ring, h3fin, flags3);
  k_out<<<1, 64, 0, stream>>>(h3fin, Wl, bl, (float*)d_out);
}